// Round 9
// baseline (134.182 us; speedup 1.0000x reference)
//
#include <hip/hip_runtime.h>
#include <hip/hip_bf16.h>
#include <math.h>

#define D_MODEL 512
#define D_FF    2048
#define NBATCH  2
#define NSEQ    384
#define NROWS   (NBATCH * NSEQ)
#define LN_EPS  1e-6f

typedef __attribute__((ext_vector_type(8))) short short8;
typedef __attribute__((ext_vector_type(4))) short short4v;
typedef __attribute__((ext_vector_type(4))) float f32x4;
typedef __hip_bfloat16 bf16;

static __device__ __forceinline__ short bfb(float x) {
    bf16 h = __float2bfloat16(x);
    return *reinterpret_cast<short*>(&h);
}

#define MFMA16(a, b, c) __builtin_amdgcn_mfma_f32_16x16x32_bf16((a), (b), (c), 0, 0, 0)

// ---------------------------------------------------------------------------
// Kernel 1: fused prep. Blocks 0..3071: weight transpose W[K][N]f32->Wt[N][K]bf16.
// Blocks 3072..3839: embed+PE row (native trig).
// ---------------------------------------------------------------------------
__global__ __launch_bounds__(256) void prep_kernel(
    const int* __restrict__ tokens, const float* __restrict__ emb,
    const float* __restrict__ Wq, const float* __restrict__ Wk,
    const float* __restrict__ Wv, const float* __restrict__ Wo,
    const float* __restrict__ W1, const float* __restrict__ W2,
    bf16* __restrict__ wqt, bf16* __restrict__ wkt, bf16* __restrict__ wvt,
    bf16* __restrict__ wot, bf16* __restrict__ w1t, bf16* __restrict__ w2t,
    float* __restrict__ x, bf16* __restrict__ xb)
{
    __shared__ float tile[32][33];
    int t = blockIdx.x;

    if (t < 3072) {
        const float* W; bf16* Wt; int K, N, bx, by;
        if (t < 1024) {
            int w = t >> 8, rem = t & 255;
            W  = (w == 0) ? Wq  : (w == 1) ? Wk  : (w == 2) ? Wv  : Wo;
            Wt = (w == 0) ? wqt : (w == 1) ? wkt : (w == 2) ? wvt : wot;
            K = 512; N = 512; bx = rem & 15; by = rem >> 4;
        } else if (t < 2048) {
            int rem = t - 1024;
            W = W1; Wt = w1t; K = 512; N = 2048; bx = rem & 63; by = rem >> 6;
        } else {
            int rem = t - 2048;
            W = W2; Wt = w2t; K = 2048; N = 512; bx = rem & 15; by = rem >> 4;
        }
        int tx = threadIdx.x & 31, ty = threadIdx.x >> 5;
        #pragma unroll
        for (int r = ty; r < 32; r += 8)
            tile[r][tx] = W[(size_t)(by * 32 + r) * N + bx * 32 + tx];
        __syncthreads();
        #pragma unroll
        for (int r = ty; r < 32; r += 8)
            Wt[(size_t)(bx * 32 + r) * K + by * 32 + tx] = __float2bfloat16(tile[tx][r]);
    } else {
        int row = t - 3072;              // b*NSEQ + n
        int n   = row % NSEQ;
        int tok = tokens[row];
        const float sqrtD = 22.627416997969522f; // sqrt(512)
        const float ESC   = 0.02595256324130752f; // log2(10000)/512
        for (int d = threadIdx.x; d < D_MODEL; d += 256) {
            float e   = emb[tok * D_MODEL + d] * sqrtD;
            float ang = (float)n * __builtin_amdgcn_exp2f(-(float)(d & ~1) * ESC);
            float pe  = (d & 1) ? __cosf(ang) : __sinf(ang);
            float val = e + pe;
            x [(size_t)row * D_MODEL + d] = val;
            xb[(size_t)row * D_MODEL + d] = __float2bfloat16(val);
        }
    }
}

// ---------------------------------------------------------------------------
// Kernel 2: fused QKV MFMA GEMM (no LDS). blockIdx.z selects q/k/v.
//  z=0: aexp = exp(2*(x@Wq+bq)); z=1: bexp = exp(2*(x@Wk+bk));
//  z=2: vT[b][d][j] = bf16(x@Wv+bv)
// ---------------------------------------------------------------------------
__global__ __launch_bounds__(256) void qkv_mfma_kernel(
    const bf16* __restrict__ A,
    const bf16* __restrict__ wqt, const bf16* __restrict__ wkt, const bf16* __restrict__ wvt,
    const float* __restrict__ bq, const float* __restrict__ bk, const float* __restrict__ bv,
    float* __restrict__ aexp, float* __restrict__ bexp, bf16* __restrict__ vT)
{
    int z = blockIdx.z;
    const bf16*  Wt   = (z == 0) ? wqt : (z == 1) ? wkt : wvt;
    const float* bias = (z == 0) ? bq  : (z == 1) ? bk  : bv;

    int lane = threadIdx.x & 63, wid = threadIdx.x >> 6;
    int rowBase = blockIdx.y * 32 + (wid >> 1) * 16;
    int colBase = blockIdx.x * 64 + (wid & 1) * 32;

    const bf16* Ap  = A  + (size_t)(rowBase + (lane & 15)) * D_MODEL + ((lane >> 4) << 3);
    const bf16* Bp0 = Wt + (size_t)(colBase + (lane & 15)) * D_MODEL + ((lane >> 4) << 3);
    const bf16* Bp1 = Bp0 + (size_t)16 * D_MODEL;

    f32x4 acc0 = {0.f, 0.f, 0.f, 0.f};
    f32x4 acc1 = {0.f, 0.f, 0.f, 0.f};

    #pragma unroll 4
    for (int k0 = 0; k0 < D_MODEL; k0 += 32) {
        short8 a  = *reinterpret_cast<const short8*>(Ap  + k0);
        short8 b0 = *reinterpret_cast<const short8*>(Bp0 + k0);
        short8 b1 = *reinterpret_cast<const short8*>(Bp1 + k0);
        acc0 = MFMA16(a, b0, acc0);
        acc1 = MFMA16(a, b1, acc1);
    }

    int crow = rowBase + ((lane >> 4) << 2);
    int ccol = colBase + (lane & 15);

    if (z < 2) {
        float* C = (z == 0) ? aexp : bexp;
        #pragma unroll
        for (int r = 0; r < 4; ++r) {
            int row = crow + r;
            #pragma unroll
            for (int j = 0; j < 2; ++j) {
                int col = ccol + j * 16;
                float val = (j == 0 ? acc0[r] : acc1[r]) + bias[col];
                C[(size_t)row * D_MODEL + col] = __expf(2.0f * val);
            }
        }
    } else {
        int bb = crow / NSEQ;
        int jr = crow - bb * NSEQ;
        #pragma unroll
        for (int j = 0; j < 2; ++j) {
            int col = ccol + j * 16;
            short4v pk;
            #pragma unroll
            for (int r = 0; r < 4; ++r)
                pk[r] = bfb((j == 0 ? acc0[r] : acc1[r]) + bias[col]);
            size_t idx = ((size_t)bb * D_MODEL + col) * NSEQ + jr;
            *reinterpret_cast<short4v*>((short*)vT + idx) = pk;
        }
    }
}

// ---------------------------------------------------------------------------
// Kernel 3: additive-attention unnormalized weights (pairwise-rcp).
// E = exp(u) bf16 unnormalized; Sp[row][quarter] = partial sums.
// grid (NROWS/4, 4); 512 thr.
// ---------------------------------------------------------------------------
__global__ __launch_bounds__(512) void score_kernel(
    const float* __restrict__ aexp, const float* __restrict__ bexp,
    const float* __restrict__ scale, bf16* __restrict__ E,
    float* __restrict__ Sp)
{
    int ig   = blockIdx.x;
    int qt   = blockIdx.y;
    int row0 = ig * 4;
    int b    = row0 / NSEQ;
    int tid  = threadIdx.x;
    int lane = tid & 63, wid = tid >> 6;

    __shared__ float sred[8][4];

    const float* ap = aexp + (size_t)row0 * D_MODEL + lane * 8;
    float a[4][8];
    #pragma unroll
    for (int r = 0; r < 4; ++r) {
        float4 A0 = *(const float4*)(ap + (size_t)r * D_MODEL);
        float4 A1 = *(const float4*)(ap + (size_t)r * D_MODEL + 4);
        a[r][0]=A0.x; a[r][1]=A0.y; a[r][2]=A0.z; a[r][3]=A0.w;
        a[r][4]=A1.x; a[r][5]=A1.y; a[r][6]=A1.z; a[r][7]=A1.w;
    }
    float4 S0 = *(const float4*)(scale + lane * 8);
    float4 S1 = *(const float4*)(scale + lane * 8 + 4);
    float sv[8] = {-2.0f*S0.x,-2.0f*S0.y,-2.0f*S0.z,-2.0f*S0.w,
                   -2.0f*S1.x,-2.0f*S1.y,-2.0f*S1.z,-2.0f*S1.w};

    const float* kb = bexp + (size_t)b * NSEQ * D_MODEL + lane * 8;
    int jb = qt * 96 + wid;

    float es[4] = {0.f, 0.f, 0.f, 0.f};

    for (int t6 = 0; t6 < 6; ++t6) {
        int j0 = jb + t6 * 16;
        int j1 = j0 + 8;
        const float4* kp0 = (const float4*)(kb + (size_t)j0 * D_MODEL);
        const float4* kp1 = (const float4*)(kb + (size_t)j1 * D_MODEL);
        float4 xa = kp0[0], xc = kp0[1];
        float4 ya = kp1[0], yc = kp1[1];
        float b0[8] = {xa.x,xa.y,xa.z,xa.w,xc.x,xc.y,xc.z,xc.w};
        float b1[8] = {ya.x,ya.y,ya.z,ya.w,yc.x,yc.y,yc.z,yc.w};

        float u[4][2] = {};
        #pragma unroll
        for (int up = 0; up < 4; ++up) {
            int d0 = up * 2, d1 = d0 + 1;
            #pragma unroll
            for (int js = 0; js < 2; ++js) {
                float xx = js ? b1[d0] : b0[d0];
                float yy = js ? b1[d1] : b0[d1];
                #pragma unroll
                for (int r = 0; r < 4; ++r) {
                    float p   = fmaf(a[r][d0], xx, 1.0f);
                    float q   = fmaf(a[r][d1], yy, 1.0f);
                    float num = fmaf(sv[d0], q, sv[d1] * p);
                    u[r][js]  = fmaf(num, __builtin_amdgcn_rcpf(p * q), u[r][js]);
                }
            }
        }

        #pragma unroll
        for (int off = 1; off < 64; off <<= 1) {
            #pragma unroll
            for (int r = 0; r < 4; ++r) {
                u[r][0] += __shfl_xor(u[r][0], off, 64);
                u[r][1] += __shfl_xor(u[r][1], off, 64);
            }
        }

        #pragma unroll
        for (int r = 0; r < 4; ++r) {
            float e0 = __expf(u[r][0]);
            float e1 = __expf(u[r][1]);
            if (lane == 0) {
                E[(size_t)(row0 + r) * NSEQ + j0] = __float2bfloat16(e0);
                E[(size_t)(row0 + r) * NSEQ + j1] = __float2bfloat16(e1);
            }
            es[r] += e0 + e1;
        }
    }

    if (lane == 0) {
        sred[wid][0] = es[0]; sred[wid][1] = es[1];
        sred[wid][2] = es[2]; sred[wid][3] = es[3];
    }
    __syncthreads();
    if (tid < 4) {
        float s = 0.0f;
        #pragma unroll
        for (int w = 0; w < 8; ++w) s += sred[w][tid];
        Sp[(size_t)(row0 + tid) * 4 + qt] = s;
    }
}

// ---------------------------------------------------------------------------
// Kernel 4: fused PV + normalize + Wo + residual + LayerNorm1.
// Block = 16 rows x 512 thr (8 waves); wave w owns cols [w*64, w*64+64).
// Phase A: attn = (E . vT) / S  -> LDS bf16.  Phase B: t1 = attn @ Wo^T + bo
// + x0 -> LDS f32.  Phase C: row LN -> x1 f32 + x1b bf16.
// ---------------------------------------------------------------------------
__global__ __launch_bounds__(512) void pv_wo_ln_kernel(
    const bf16* __restrict__ E, const bf16* __restrict__ vT,
    const float* __restrict__ Sp, const bf16* __restrict__ wot,
    const float* __restrict__ bo, const float* __restrict__ x0,
    const float* __restrict__ g1, const float* __restrict__ beta1,
    float* __restrict__ x1, bf16* __restrict__ x1b)
{
    int row0 = blockIdx.x * 16;      // 48 blocks; 384 % 16 == 0 -> same batch
    int b    = row0 / NSEQ;
    int tid  = threadIdx.x;
    int lane = tid & 63, wid = tid >> 6;
    int colBase = wid * 64;

    __shared__ bf16  attnS[16][D_MODEL + 8];   // +8 bf16 pad: 2-way max conflicts
    __shared__ float t1f  [16][D_MODEL + 4];

    int arow = lane & 15;            // A-fragment row
    int koff = (lane >> 4) << 3;     // A/B k-slice start
    int crow = (lane >> 4) << 2;     // C/D local row base
    int ccol = lane & 15;            // C/D col within 16-tile

    // ---- phase A: PV, K = NSEQ = 384 (12 steps)
    {
        const bf16* Ap = E + ((size_t)(row0 + arow)) * NSEQ + koff;
        const bf16* Bp = vT + ((size_t)b * D_MODEL + colBase + arow) * NSEQ + koff;
        f32x4 p0 = {0,0,0,0}, p1 = {0,0,0,0}, p2 = {0,0,0,0}, p3 = {0,0,0,0};
        #pragma unroll
        for (int k0 = 0; k0 < NSEQ; k0 += 32) {
            short8 a  = *(const short8*)(Ap + k0);
            short8 v0 = *(const short8*)(Bp + k0);
            short8 v1 = *(const short8*)(Bp + (size_t)16 * NSEQ + k0);
            short8 v2 = *(const short8*)(Bp + (size_t)32 * NSEQ + k0);
            short8 v3 = *(const short8*)(Bp + (size_t)48 * NSEQ + k0);
            p0 = MFMA16(a, v0, p0);
            p1 = MFMA16(a, v1, p1);
            p2 = MFMA16(a, v2, p2);
            p3 = MFMA16(a, v3, p3);
        }
        #pragma unroll
        for (int r = 0; r < 4; ++r) {
            int lrow = crow + r;
            float4 sp4 = *(const float4*)(Sp + (size_t)(row0 + lrow) * 4);
            float Sinv = 1.0f / (sp4.x + sp4.y + sp4.z + sp4.w);
            attnS[lrow][colBase +  0 + ccol] = __float2bfloat16(p0[r] * Sinv);
            attnS[lrow][colBase + 16 + ccol] = __float2bfloat16(p1[r] * Sinv);
            attnS[lrow][colBase + 32 + ccol] = __float2bfloat16(p2[r] * Sinv);
            attnS[lrow][colBase + 48 + ccol] = __float2bfloat16(p3[r] * Sinv);
        }
    }
    __syncthreads();

    // ---- phase B: Wo, K = D_MODEL = 512 (16 steps), A from LDS
    {
        const bf16* Wp = wot + ((size_t)(colBase + arow)) * D_MODEL + koff;
        f32x4 w0 = {0,0,0,0}, w1 = {0,0,0,0}, w2 = {0,0,0,0}, w3 = {0,0,0,0};
        #pragma unroll
        for (int k0 = 0; k0 < D_MODEL; k0 += 32) {
            short8 a  = *(const short8*)(&attnS[arow][k0 + koff]);
            short8 q0 = *(const short8*)(Wp + k0);
            short8 q1 = *(const short8*)(Wp + (size_t)16 * D_MODEL + k0);
            short8 q2 = *(const short8*)(Wp + (size_t)32 * D_MODEL + k0);
            short8 q3 = *(const short8*)(Wp + (size_t)48 * D_MODEL + k0);
            w0 = MFMA16(a, q0, w0);
            w1 = MFMA16(a, q1, w1);
            w2 = MFMA16(a, q2, w2);
            w3 = MFMA16(a, q3, w3);
        }
        #pragma unroll
        for (int r = 0; r < 4; ++r) {
            int lrow = crow + r;
            size_t grow = (size_t)(row0 + lrow);
            int c0 = colBase + ccol;
            t1f[lrow][c0     ] = w0[r] + bo[c0     ] + x0[grow * D_MODEL + c0     ];
            t1f[lrow][c0 + 16] = w1[r] + bo[c0 + 16] + x0[grow * D_MODEL + c0 + 16];
            t1f[lrow][c0 + 32] = w2[r] + bo[c0 + 32] + x0[grow * D_MODEL + c0 + 32];
            t1f[lrow][c0 + 48] = w3[r] + bo[c0 + 48] + x0[grow * D_MODEL + c0 + 48];
        }
    }
    __syncthreads();

    // ---- phase C: LayerNorm, 2 rows per wave
    #pragma unroll
    for (int rr = 0; rr < 2; ++rr) {
        int lrow = wid * 2 + rr;
        size_t grow = (size_t)(row0 + lrow);
        float v[8];
        #pragma unroll
        for (int u = 0; u < 8; ++u) v[u] = t1f[lrow][lane * 8 + u];
        float s = 0.0f;
        #pragma unroll
        for (int u = 0; u < 8; ++u) s += v[u];
        #pragma unroll
        for (int off = 1; off < 64; off <<= 1) s += __shfl_xor(s, off, 64);
        float mu = s * (1.0f / D_MODEL);
        float s2 = 0.0f;
        #pragma unroll
        for (int u = 0; u < 8; ++u) { float d = v[u] - mu; s2 += d * d; }
        #pragma unroll
        for (int off = 1; off < 64; off <<= 1) s2 += __shfl_xor(s2, off, 64);
        float inv = rsqrtf(s2 * (1.0f / D_MODEL) + LN_EPS);
        #pragma unroll
        for (int u = 0; u < 8; ++u) {
            int c = lane * 8 + u;
            float o = (v[u] - mu) * inv * g1[c] + beta1[c];
            x1 [grow * D_MODEL + c] = o;
            x1b[grow * D_MODEL + c] = __float2bfloat16(o);
        }
    }
}

// ---------------------------------------------------------------------------
// Kernel 5: generic bf16 MFMA GEMM (no LDS): C = A @ Wt^T + bias (+relu)
// (used for FF-up)
// ---------------------------------------------------------------------------
__global__ __launch_bounds__(256) void mfma_gemm_kernel(
    const bf16* __restrict__ A, const bf16* __restrict__ Wt,
    const float* __restrict__ bias,
    bf16* __restrict__ Cb, int K, int N, int relu)
{
    int lane = threadIdx.x & 63, wid = threadIdx.x >> 6;
    int rowBase = blockIdx.y * 32 + (wid >> 1) * 16;
    int colBase = blockIdx.x * 64 + (wid & 1) * 32;

    const bf16* Ap  = A  + (size_t)(rowBase + (lane & 15)) * K + ((lane >> 4) << 3);
    const bf16* Bp0 = Wt + (size_t)(colBase + (lane & 15)) * K + ((lane >> 4) << 3);
    const bf16* Bp1 = Bp0 + (size_t)16 * K;

    f32x4 acc0 = {0.f, 0.f, 0.f, 0.f};
    f32x4 acc1 = {0.f, 0.f, 0.f, 0.f};

    #pragma unroll 4
    for (int k0 = 0; k0 < K; k0 += 32) {
        short8 a  = *reinterpret_cast<const short8*>(Ap  + k0);
        short8 b0 = *reinterpret_cast<const short8*>(Bp0 + k0);
        short8 b1 = *reinterpret_cast<const short8*>(Bp1 + k0);
        acc0 = MFMA16(a, b0, acc0);
        acc1 = MFMA16(a, b1, acc1);
    }

    int crow = rowBase + ((lane >> 4) << 2);
    int ccol = colBase + (lane & 15);
    #pragma unroll
    for (int r = 0; r < 4; ++r) {
        int row = crow + r;
        #pragma unroll
        for (int j = 0; j < 2; ++j) {
            int col = ccol + j * 16;
            float val = (j == 0 ? acc0[r] : acc1[r]) + bias[col];
            if (relu) val = fmaxf(val, 0.0f);
            Cb[(size_t)row * N + col] = __float2bfloat16(val);
        }
    }
}

// ---------------------------------------------------------------------------
// Kernel 6: FF-down with 2-way K-split (z = K-half). z=0 adds bias+resid -> y0;
// z=1 plain partial -> y1. Combined in LN2.
// ---------------------------------------------------------------------------
__global__ __launch_bounds__(256) void ffdown_kernel(
    const bf16* __restrict__ A, const bf16* __restrict__ Wt,
    const float* __restrict__ bias, const float* __restrict__ resid,
    float* __restrict__ y0, float* __restrict__ y1)
{
    int z = blockIdx.z;
    int kbeg = z * (D_FF / 2);
    int lane = threadIdx.x & 63, wid = threadIdx.x >> 6;
    int rowBase = blockIdx.y * 32 + (wid >> 1) * 16;
    int colBase = blockIdx.x * 64 + (wid & 1) * 32;

    const bf16* Ap  = A  + (size_t)(rowBase + (lane & 15)) * D_FF + kbeg + ((lane >> 4) << 3);
    const bf16* Bp0 = Wt + (size_t)(colBase + (lane & 15)) * D_FF + kbeg + ((lane >> 4) << 3);
    const bf16* Bp1 = Bp0 + (size_t)16 * D_FF;

    f32x4 acc0 = {0.f, 0.f, 0.f, 0.f};
    f32x4 acc1 = {0.f, 0.f, 0.f, 0.f};

    #pragma unroll 4
    for (int k0 = 0; k0 < D_FF / 2; k0 += 32) {
        short8 a  = *reinterpret_cast<const short8*>(Ap  + k0);
        short8 b0 = *reinterpret_cast<const short8*>(Bp0 + k0);
        short8 b1 = *reinterpret_cast<const short8*>(Bp1 + k0);
        acc0 = MFMA16(a, b0, acc0);
        acc1 = MFMA16(a, b1, acc1);
    }

    int crow = rowBase + ((lane >> 4) << 2);
    int ccol = colBase + (lane & 15);
    #pragma unroll
    for (int r = 0; r < 4; ++r) {
        int row = crow + r;
        #pragma unroll
        for (int j = 0; j < 2; ++j) {
            int col = ccol + j * 16;
            float val = (j == 0 ? acc0[r] : acc1[r]);
            if (z == 0) {
                val += bias[col] + resid[(size_t)row * D_MODEL + col];
                y0[(size_t)row * D_MODEL + col] = val;
            } else {
                y1[(size_t)row * D_MODEL + col] = val;
            }
        }
    }
}

// ---------------------------------------------------------------------------
// Kernel 7: LayerNorm over last dim (512); in2 optional (summed partials)
// ---------------------------------------------------------------------------
__global__ __launch_bounds__(256) void ln_kernel(
    const float* __restrict__ in, const float* __restrict__ in2,
    const float* __restrict__ gamma, const float* __restrict__ beta,
    float* __restrict__ out)
{
    int row = blockIdx.x;
    int tid = threadIdx.x;
    int lane = tid & 63, wid = tid >> 6;
    __shared__ float red[4];

    float v0 = in[(size_t)row * D_MODEL + tid];
    float v1 = in[(size_t)row * D_MODEL + tid + 256];
    if (in2) {
        v0 += in2[(size_t)row * D_MODEL + tid];
        v1 += in2[(size_t)row * D_MODEL + tid + 256];
    }

    float s = v0 + v1;
    #pragma unroll
    for (int off = 32; off; off >>= 1) s += __shfl_xor(s, off, 64);
    if (lane == 0) red[wid] = s;
    __syncthreads();
    if (tid == 0) red[0] = red[0] + red[1] + red[2] + red[3];
    __syncthreads();
    float mu = red[0] * (1.0f / D_MODEL);
    __syncthreads();

    float d0 = v0 - mu, d1 = v1 - mu;
    float s2 = d0 * d0 + d1 * d1;
    #pragma unroll
    for (int off = 32; off; off >>= 1) s2 += __shfl_xor(s2, off, 64);
    if (lane == 0) red[wid] = s2;
    __syncthreads();
    if (tid == 0) red[0] = red[0] + red[1] + red[2] + red[3];
    __syncthreads();
    float var = red[0] * (1.0f / D_MODEL);
    float inv = rsqrtf(var + LN_EPS);

    out[(size_t)row * D_MODEL + tid]       = d0 * inv * gamma[tid] + beta[tid];
    out[(size_t)row * D_MODEL + tid + 256] = d1 * inv * gamma[tid + 256] + beta[tid + 256];
}

// ---------------------------------------------------------------------------
extern "C" void kernel_launch(void* const* d_in, const int* in_sizes, int n_in,
                              void* d_out, int out_size, void* d_ws, size_t ws_size,
                              hipStream_t stream)
{
    const int*   tokens = (const int*)  d_in[0];
    const float* emb    = (const float*)d_in[1];
    const float* Wq     = (const float*)d_in[2];
    const float* bq     = (const float*)d_in[3];
    const float* Wk     = (const float*)d_in[4];
    const float* bk     = (const float*)d_in[5];
    const float* Wv     = (const float*)d_in[6];
    const float* bv     = (const float*)d_in[7];
    const float* ascale = (const float*)d_in[8];
    const float* Wo     = (const float*)d_in[9];
    const float* bo     = (const float*)d_in[10];
    const float* g1     = (const float*)d_in[11];
    const float* beta1  = (const float*)d_in[12];
    const float* W1     = (const float*)d_in[13];
    const float* bf1    = (const float*)d_in[14];
    const float* W2     = (const float*)d_in[15];
    const float* bf2    = (const float*)d_in[16];
    const float* g2     = (const float*)d_in[17];
    const float* beta2  = (const float*)d_in[18];

    float* out = (float*)d_out;
    float* ws  = (float*)d_ws;

    const size_t SZ = (size_t)NROWS * D_MODEL;   // 393216

    float* x0   = ws;            // embed out; Wo residual; then y1 (ffdown z=1)
    float* aexp = ws + 1 * SZ;   // exp(2q); after score -> x1 (LN1 out, ffdown resid, y0 in-place)
    float* bexp = ws + 2 * SZ;   // exp(2k); dead after score
    float* x1 = aexp;
    float* y0 = x1;              // in-place: same thread reads resid then writes
    float* y1 = bexp;

    bf16* x0b   = (bf16*)(ws + 3 * SZ);
    bf16* x1b   = x0b + SZ;
    bf16* hb    = x1b + SZ;                          // NROWS * D_FF
    bf16* Eb    = hb + (size_t)NROWS * D_FF;         // 2*384*384
    bf16* vTb   = Eb + (size_t)NBATCH * NSEQ * NSEQ; // 2*512*384
    bf16* wqt   = vTb + (size_t)NBATCH * D_MODEL * NSEQ;
    bf16* wkt   = wqt + (size_t)D_MODEL * D_MODEL;
    bf16* wvt   = wkt + (size_t)D_MODEL * D_MODEL;
    bf16* wot   = wvt + (size_t)D_MODEL * D_MODEL;
    bf16* w1t   = wot + (size_t)D_MODEL * D_MODEL;   // [D_FF][D_MODEL]
    bf16* w2t   = w1t + (size_t)D_MODEL * D_FF;      // [D_MODEL][D_FF]
    float* Sp   = (float*)(w2t + (size_t)D_FF * D_MODEL);  // [NROWS][4]

    // 1. weight transposes + embed/PE
    prep_kernel<<<3072 + NROWS, 256, 0, stream>>>(
        tokens, emb, Wq, Wk, Wv, Wo, W1, W2,
        wqt, wkt, wvt, wot, w1t, w2t, x0, x0b);

    // 2. fused QKV (z: 0->aexp, 1->bexp, 2->vT bf16)
    qkv_mfma_kernel<<<dim3(D_MODEL / 64, NROWS / 32, 3), 256, 0, stream>>>(
        x0b, wqt, wkt, wvt, bq, bk, bv, aexp, bexp, vTb);

    // 3. unnormalized attention weights E + partial row-sums Sp
    score_kernel<<<dim3(NROWS / 4, 4), 512, 0, stream>>>(aexp, bexp, ascale, Eb, Sp);

    // 4. fused PV + normalize + Wo + residual + LN1 -> x1 f32 + x1b bf16
    pv_wo_ln_kernel<<<NROWS / 16, 512, 0, stream>>>(
        Eb, vTb, Sp, wot, bo, x0, g1, beta1, x1, x1b);

    // 5. FF up + ReLU -> hb bf16
    mfma_gemm_kernel<<<dim3(D_FF / 64, NROWS / 32), 256, 0, stream>>>(
        x1b, w1t, bf1, hb, D_MODEL, D_FF, 1);

    // 6. FF down, 2-way K-split: y0 = partial + bias + resid (in-place on x1), y1 = partial
    ffdown_kernel<<<dim3(D_MODEL / 64, NROWS / 32, 2), 256, 0, stream>>>(
        hb, w2t, bf2, x1, y0, y1);

    // 7. LayerNorm 2 over (y0 + y1) -> out
    ln_kernel<<<NROWS, 256, 0, stream>>>(y0, y1, g2, beta2, out);
}

// Round 10
// 130.499 us; speedup vs baseline: 1.0282x; 1.0282x over previous
//
#include <hip/hip_runtime.h>
#include <hip/hip_bf16.h>
#include <math.h>

#define D_MODEL 512
#define D_FF    2048
#define NBATCH  2
#define NSEQ    384
#define NROWS   (NBATCH * NSEQ)
#define LN_EPS  1e-6f

typedef __attribute__((ext_vector_type(8))) short short8;
typedef __attribute__((ext_vector_type(4))) short short4v;
typedef __attribute__((ext_vector_type(4))) float f32x4;
typedef __hip_bfloat16 bf16;

static __device__ __forceinline__ short bfb(float x) {
    bf16 h = __float2bfloat16(x);
    return *reinterpret_cast<short*>(&h);
}

#define MFMA16(a, b, c) __builtin_amdgcn_mfma_f32_16x16x32_bf16((a), (b), (c), 0, 0, 0)

// ---------------------------------------------------------------------------
// Kernel 1: fused prep. Blocks 0..3071: weight transpose W[K][N]f32->Wt[N][K]bf16.
// Blocks 3072..3839: embed+PE row (native trig).
// ---------------------------------------------------------------------------
__global__ __launch_bounds__(256) void prep_kernel(
    const int* __restrict__ tokens, const float* __restrict__ emb,
    const float* __restrict__ Wq, const float* __restrict__ Wk,
    const float* __restrict__ Wv, const float* __restrict__ Wo,
    const float* __restrict__ W1, const float* __restrict__ W2,
    bf16* __restrict__ wqt, bf16* __restrict__ wkt, bf16* __restrict__ wvt,
    bf16* __restrict__ wot, bf16* __restrict__ w1t, bf16* __restrict__ w2t,
    float* __restrict__ x, bf16* __restrict__ xb)
{
    __shared__ float tile[32][33];
    int t = blockIdx.x;

    if (t < 3072) {
        const float* W; bf16* Wt; int K, N, bx, by;
        if (t < 1024) {
            int w = t >> 8, rem = t & 255;
            W  = (w == 0) ? Wq  : (w == 1) ? Wk  : (w == 2) ? Wv  : Wo;
            Wt = (w == 0) ? wqt : (w == 1) ? wkt : (w == 2) ? wvt : wot;
            K = 512; N = 512; bx = rem & 15; by = rem >> 4;
        } else if (t < 2048) {
            int rem = t - 1024;
            W = W1; Wt = w1t; K = 512; N = 2048; bx = rem & 63; by = rem >> 6;
        } else {
            int rem = t - 2048;
            W = W2; Wt = w2t; K = 2048; N = 512; bx = rem & 15; by = rem >> 4;
        }
        int tx = threadIdx.x & 31, ty = threadIdx.x >> 5;
        #pragma unroll
        for (int r = ty; r < 32; r += 8)
            tile[r][tx] = W[(size_t)(by * 32 + r) * N + bx * 32 + tx];
        __syncthreads();
        #pragma unroll
        for (int r = ty; r < 32; r += 8)
            Wt[(size_t)(bx * 32 + r) * K + by * 32 + tx] = __float2bfloat16(tile[tx][r]);
    } else {
        int row = t - 3072;              // b*NSEQ + n
        int n   = row % NSEQ;
        int tok = tokens[row];
        const float sqrtD = 22.627416997969522f; // sqrt(512)
        const float ESC   = 0.02595256324130752f; // log2(10000)/512
        for (int d = threadIdx.x; d < D_MODEL; d += 256) {
            float e   = emb[tok * D_MODEL + d] * sqrtD;
            float ang = (float)n * __builtin_amdgcn_exp2f(-(float)(d & ~1) * ESC);
            float pe  = (d & 1) ? __cosf(ang) : __sinf(ang);
            float val = e + pe;
            x [(size_t)row * D_MODEL + d] = val;
            xb[(size_t)row * D_MODEL + d] = __float2bfloat16(val);
        }
    }
}

// ---------------------------------------------------------------------------
// Kernel 2: fused QKV MFMA GEMM (no LDS). blockIdx.z selects q/k/v.
//  z=0: aexp = exp(2*(x@Wq+bq)); z=1: bexp = exp(2*(x@Wk+bk));
//  z=2: vb[row][d] = bf16(x@Wv+bv)   (plain layout; PV is d-sliced per wave)
// ---------------------------------------------------------------------------
__global__ __launch_bounds__(256) void qkv_mfma_kernel(
    const bf16* __restrict__ A,
    const bf16* __restrict__ wqt, const bf16* __restrict__ wkt, const bf16* __restrict__ wvt,
    const float* __restrict__ bq, const float* __restrict__ bk, const float* __restrict__ bv,
    float* __restrict__ aexp, float* __restrict__ bexp, bf16* __restrict__ vb)
{
    int z = blockIdx.z;
    const bf16*  Wt   = (z == 0) ? wqt : (z == 1) ? wkt : wvt;
    const float* bias = (z == 0) ? bq  : (z == 1) ? bk  : bv;

    int lane = threadIdx.x & 63, wid = threadIdx.x >> 6;
    int rowBase = blockIdx.y * 32 + (wid >> 1) * 16;
    int colBase = blockIdx.x * 64 + (wid & 1) * 32;

    const bf16* Ap  = A  + (size_t)(rowBase + (lane & 15)) * D_MODEL + ((lane >> 4) << 3);
    const bf16* Bp0 = Wt + (size_t)(colBase + (lane & 15)) * D_MODEL + ((lane >> 4) << 3);
    const bf16* Bp1 = Bp0 + (size_t)16 * D_MODEL;

    f32x4 acc0 = {0.f, 0.f, 0.f, 0.f};
    f32x4 acc1 = {0.f, 0.f, 0.f, 0.f};

    #pragma unroll 4
    for (int k0 = 0; k0 < D_MODEL; k0 += 32) {
        short8 a  = *reinterpret_cast<const short8*>(Ap  + k0);
        short8 b0 = *reinterpret_cast<const short8*>(Bp0 + k0);
        short8 b1 = *reinterpret_cast<const short8*>(Bp1 + k0);
        acc0 = MFMA16(a, b0, acc0);
        acc1 = MFMA16(a, b1, acc1);
    }

    int crow = rowBase + ((lane >> 4) << 2);
    int ccol = colBase + (lane & 15);

    if (z < 2) {
        float* C = (z == 0) ? aexp : bexp;
        #pragma unroll
        for (int r = 0; r < 4; ++r) {
            int row = crow + r;
            #pragma unroll
            for (int j = 0; j < 2; ++j) {
                int col = ccol + j * 16;
                float val = (j == 0 ? acc0[r] : acc1[r]) + bias[col];
                C[(size_t)row * D_MODEL + col] = __expf(2.0f * val);
            }
        }
    } else {
        #pragma unroll
        for (int r = 0; r < 4; ++r) {
            int row = crow + r;
            #pragma unroll
            for (int j = 0; j < 2; ++j) {
                int col = ccol + j * 16;
                float val = (j == 0 ? acc0[r] : acc1[r]) + bias[col];
                vb[(size_t)row * D_MODEL + col] = __float2bfloat16(val);
            }
        }
    }
}

// ---------------------------------------------------------------------------
// Kernel 3: fused score + PV (quarter-partial).
// Phase 1 (score): u_ij = sum_d sv_d * rcp(a_id*b_jd+1), pairwise-rcp; e=exp(u)
// -> LDS Et[4][96]; Sp[row][qt] = partial sum.
// Phase 2 (PV): wave w owns d-slice [w*64,(w+1)*64); lane owns one d.
// attn_q[qt][row][d] = sum_{j in quarter} e * v[j][d]   (f32 partial)
// grid (NROWS/4, 4); 512 thr.
// ---------------------------------------------------------------------------
__global__ __launch_bounds__(512) void scorepv_kernel(
    const float* __restrict__ aexp, const float* __restrict__ bexp,
    const float* __restrict__ scale, const bf16* __restrict__ vb,
    float* __restrict__ attn_q, float* __restrict__ Sp)
{
    int ig   = blockIdx.x;
    int qt   = blockIdx.y;
    int row0 = ig * 4;
    int b    = row0 / NSEQ;
    int tid  = threadIdx.x;
    int lane = tid & 63, wid = tid >> 6;

    __shared__ float Et[4][96];
    __shared__ float sred[8][4];

    const float* ap = aexp + (size_t)row0 * D_MODEL + lane * 8;
    float a[4][8];
    #pragma unroll
    for (int r = 0; r < 4; ++r) {
        float4 A0 = *(const float4*)(ap + (size_t)r * D_MODEL);
        float4 A1 = *(const float4*)(ap + (size_t)r * D_MODEL + 4);
        a[r][0]=A0.x; a[r][1]=A0.y; a[r][2]=A0.z; a[r][3]=A0.w;
        a[r][4]=A1.x; a[r][5]=A1.y; a[r][6]=A1.z; a[r][7]=A1.w;
    }
    float4 S0 = *(const float4*)(scale + lane * 8);
    float4 S1 = *(const float4*)(scale + lane * 8 + 4);
    float sv[8] = {-2.0f*S0.x,-2.0f*S0.y,-2.0f*S0.z,-2.0f*S0.w,
                   -2.0f*S1.x,-2.0f*S1.y,-2.0f*S1.z,-2.0f*S1.w};

    const float* kb = bexp + (size_t)b * NSEQ * D_MODEL + lane * 8;
    int jb = qt * 96 + wid;

    float es[4] = {0.f, 0.f, 0.f, 0.f};

    for (int t6 = 0; t6 < 6; ++t6) {
        int jl0 = wid + t6 * 16;       // local j in [0,96)
        int jl1 = jl0 + 8;
        int j0 = qt * 96 + jl0;
        int j1 = j0 + 8;
        const float4* kp0 = (const float4*)(kb + (size_t)j0 * D_MODEL);
        const float4* kp1 = (const float4*)(kb + (size_t)j1 * D_MODEL);
        float4 xa = kp0[0], xc = kp0[1];
        float4 ya = kp1[0], yc = kp1[1];
        float b0[8] = {xa.x,xa.y,xa.z,xa.w,xc.x,xc.y,xc.z,xc.w};
        float b1[8] = {ya.x,ya.y,ya.z,ya.w,yc.x,yc.y,yc.z,yc.w};

        float u[4][2] = {};
        #pragma unroll
        for (int up = 0; up < 4; ++up) {
            int d0 = up * 2, d1 = d0 + 1;
            #pragma unroll
            for (int js = 0; js < 2; ++js) {
                float xx = js ? b1[d0] : b0[d0];
                float yy = js ? b1[d1] : b0[d1];
                #pragma unroll
                for (int r = 0; r < 4; ++r) {
                    float p   = fmaf(a[r][d0], xx, 1.0f);
                    float q   = fmaf(a[r][d1], yy, 1.0f);
                    float num = fmaf(sv[d0], q, sv[d1] * p);
                    u[r][js]  = fmaf(num, __builtin_amdgcn_rcpf(p * q), u[r][js]);
                }
            }
        }

        #pragma unroll
        for (int off = 1; off < 64; off <<= 1) {
            #pragma unroll
            for (int r = 0; r < 4; ++r) {
                u[r][0] += __shfl_xor(u[r][0], off, 64);
                u[r][1] += __shfl_xor(u[r][1], off, 64);
            }
        }

        #pragma unroll
        for (int r = 0; r < 4; ++r) {
            float e0 = __expf(u[r][0]);
            float e1 = __expf(u[r][1]);
            if (lane == 0) { Et[r][jl0] = e0; Et[r][jl1] = e1; }
            es[r] += e0 + e1;
        }
    }

    if (lane == 0) {
        sred[wid][0] = es[0]; sred[wid][1] = es[1];
        sred[wid][2] = es[2]; sred[wid][3] = es[3];
    }
    __syncthreads();
    if (tid < 4) {
        float s = 0.0f;
        #pragma unroll
        for (int w = 0; w < 8; ++w) s += sred[w][tid];
        Sp[(size_t)(row0 + tid) * 4 + qt] = s;
    }

    // ---- phase 2: PV over this quarter's 96 j's; wave owns 64-d slice
    int d = wid * 64 + lane;
    const bf16* vcol = vb + ((size_t)b * NSEQ + qt * 96) * D_MODEL + d;
    float pacc[4] = {0.f, 0.f, 0.f, 0.f};
    #pragma unroll 4
    for (int j = 0; j < 96; ++j) {
        float vf = __bfloat162float(vcol[(size_t)j * D_MODEL]);
        pacc[0] = fmaf(Et[0][j], vf, pacc[0]);
        pacc[1] = fmaf(Et[1][j], vf, pacc[1]);
        pacc[2] = fmaf(Et[2][j], vf, pacc[2]);
        pacc[3] = fmaf(Et[3][j], vf, pacc[3]);
    }
    size_t qbase = (size_t)qt * NROWS * D_MODEL;
    #pragma unroll
    for (int r = 0; r < 4; ++r)
        attn_q[qbase + (size_t)(row0 + r) * D_MODEL + d] = pacc[r];
}

// ---------------------------------------------------------------------------
// Kernel 4: Wo GEMM with fused quarter-combine + normalize.
// Prologue: attn = (sum_q attn_q) * Sinv -> bf16 LDS tile [32][512].
// Then MFMA: t1 = attn @ Wo^T + bo + x0.  grid (8, 24) = 192 blocks.
// ---------------------------------------------------------------------------
__global__ __launch_bounds__(256) void wo_kernel(
    const float* __restrict__ attn_q, const float* __restrict__ Sp,
    const bf16* __restrict__ wot, const float* __restrict__ bo,
    const float* __restrict__ x0, float* __restrict__ t1)
{
    int rowBase = blockIdx.y * 32;
    int colBase = blockIdx.x * 64;
    int tid = threadIdx.x;

    __shared__ bf16  attnS[32][D_MODEL + 8];   // row stride 1040B (16B-mult)
    __shared__ float sinvS[32];

    if (tid < 32) {
        float4 s4 = *(const float4*)(Sp + (size_t)(rowBase + tid) * 4);
        sinvS[tid] = 1.0f / (s4.x + s4.y + s4.z + s4.w);
    }
    __syncthreads();

    const size_t Q = (size_t)NROWS * D_MODEL;
    #pragma unroll
    for (int i = tid; i < 32 * D_MODEL / 4; i += 256) {
        int r  = i >> 7;              // 128 float4 per row
        int d4 = (i & 127) << 2;
        size_t off = (size_t)(rowBase + r) * D_MODEL + d4;
        float4 v0 = *(const float4*)(attn_q + off);
        float4 v1 = *(const float4*)(attn_q + Q + off);
        float4 v2 = *(const float4*)(attn_q + 2 * Q + off);
        float4 v3 = *(const float4*)(attn_q + 3 * Q + off);
        float si = sinvS[r];
        short4v pk;
        pk[0] = bfb((v0.x + v1.x + v2.x + v3.x) * si);
        pk[1] = bfb((v0.y + v1.y + v2.y + v3.y) * si);
        pk[2] = bfb((v0.z + v1.z + v2.z + v3.z) * si);
        pk[3] = bfb((v0.w + v1.w + v2.w + v3.w) * si);
        *reinterpret_cast<short4v*>(&attnS[r][d4]) = pk;
    }
    __syncthreads();

    int lane = tid & 63, wid = tid >> 6;
    int wrow = (wid >> 1) * 16;
    int wcol = colBase + (wid & 1) * 32;
    int arow = lane & 15, koff = (lane >> 4) << 3;

    const bf16* Bp0 = wot + (size_t)(wcol + arow) * D_MODEL + koff;
    const bf16* Bp1 = Bp0 + (size_t)16 * D_MODEL;

    f32x4 acc0 = {0.f, 0.f, 0.f, 0.f};
    f32x4 acc1 = {0.f, 0.f, 0.f, 0.f};

    #pragma unroll 4
    for (int k0 = 0; k0 < D_MODEL; k0 += 32) {
        short8 a  = *reinterpret_cast<const short8*>(&attnS[wrow + arow][k0 + koff]);
        short8 b0 = *reinterpret_cast<const short8*>(Bp0 + k0);
        short8 b1 = *reinterpret_cast<const short8*>(Bp1 + k0);
        acc0 = MFMA16(a, b0, acc0);
        acc1 = MFMA16(a, b1, acc1);
    }

    int crow = rowBase + wrow + ((lane >> 4) << 2);
    int ccol = wcol + (lane & 15);
    #pragma unroll
    for (int r = 0; r < 4; ++r) {
        int row = crow + r;
        #pragma unroll
        for (int j = 0; j < 2; ++j) {
            int col = ccol + j * 16;
            float val = (j == 0 ? acc0[r] : acc1[r]) + bo[col]
                      + x0[(size_t)row * D_MODEL + col];
            t1[(size_t)row * D_MODEL + col] = val;
        }
    }
}

// ---------------------------------------------------------------------------
// Kernel 5: generic bf16 MFMA GEMM (no LDS): Cb = A @ Wt^T + bias (+relu)
// ---------------------------------------------------------------------------
__global__ __launch_bounds__(256) void mfma_gemm_kernel(
    const bf16* __restrict__ A, const bf16* __restrict__ Wt,
    const float* __restrict__ bias,
    bf16* __restrict__ Cb, int K, int N, int relu)
{
    int lane = threadIdx.x & 63, wid = threadIdx.x >> 6;
    int rowBase = blockIdx.y * 32 + (wid >> 1) * 16;
    int colBase = blockIdx.x * 64 + (wid & 1) * 32;

    const bf16* Ap  = A  + (size_t)(rowBase + (lane & 15)) * K + ((lane >> 4) << 3);
    const bf16* Bp0 = Wt + (size_t)(colBase + (lane & 15)) * K + ((lane >> 4) << 3);
    const bf16* Bp1 = Bp0 + (size_t)16 * K;

    f32x4 acc0 = {0.f, 0.f, 0.f, 0.f};
    f32x4 acc1 = {0.f, 0.f, 0.f, 0.f};

    #pragma unroll 4
    for (int k0 = 0; k0 < K; k0 += 32) {
        short8 a  = *reinterpret_cast<const short8*>(Ap  + k0);
        short8 b0 = *reinterpret_cast<const short8*>(Bp0 + k0);
        short8 b1 = *reinterpret_cast<const short8*>(Bp1 + k0);
        acc0 = MFMA16(a, b0, acc0);
        acc1 = MFMA16(a, b1, acc1);
    }

    int crow = rowBase + ((lane >> 4) << 2);
    int ccol = colBase + (lane & 15);
    #pragma unroll
    for (int r = 0; r < 4; ++r) {
        int row = crow + r;
        #pragma unroll
        for (int j = 0; j < 2; ++j) {
            int col = ccol + j * 16;
            float val = (j == 0 ? acc0[r] : acc1[r]) + bias[col];
            if (relu) val = fmaxf(val, 0.0f);
            Cb[(size_t)row * N + col] = __float2bfloat16(val);
        }
    }
}

// ---------------------------------------------------------------------------
// Kernel 6: FF-down with 2-way K-split (z = K-half). z=0 adds bias+resid -> y0;
// z=1 plain partial -> y1. Combined in LN2.
// ---------------------------------------------------------------------------
__global__ __launch_bounds__(256) void ffdown_kernel(
    const bf16* __restrict__ A, const bf16* __restrict__ Wt,
    const float* __restrict__ bias, const float* __restrict__ resid,
    float* __restrict__ y0, float* __restrict__ y1)
{
    int z = blockIdx.z;
    int kbeg = z * (D_FF / 2);
    int lane = threadIdx.x & 63, wid = threadIdx.x >> 6;
    int rowBase = blockIdx.y * 32 + (wid >> 1) * 16;
    int colBase = blockIdx.x * 64 + (wid & 1) * 32;

    const bf16* Ap  = A  + (size_t)(rowBase + (lane & 15)) * D_FF + kbeg + ((lane >> 4) << 3);
    const bf16* Bp0 = Wt + (size_t)(colBase + (lane & 15)) * D_FF + kbeg + ((lane >> 4) << 3);
    const bf16* Bp1 = Bp0 + (size_t)16 * D_FF;

    f32x4 acc0 = {0.f, 0.f, 0.f, 0.f};
    f32x4 acc1 = {0.f, 0.f, 0.f, 0.f};

    #pragma unroll 4
    for (int k0 = 0; k0 < D_FF / 2; k0 += 32) {
        short8 a  = *reinterpret_cast<const short8*>(Ap  + k0);
        short8 b0 = *reinterpret_cast<const short8*>(Bp0 + k0);
        short8 b1 = *reinterpret_cast<const short8*>(Bp1 + k0);
        acc0 = MFMA16(a, b0, acc0);
        acc1 = MFMA16(a, b1, acc1);
    }

    int crow = rowBase + ((lane >> 4) << 2);
    int ccol = colBase + (lane & 15);
    #pragma unroll
    for (int r = 0; r < 4; ++r) {
        int row = crow + r;
        #pragma unroll
        for (int j = 0; j < 2; ++j) {
            int col = ccol + j * 16;
            float val = (j == 0 ? acc0[r] : acc1[r]);
            if (z == 0) {
                val += bias[col] + resid[(size_t)row * D_MODEL + col];
                y0[(size_t)row * D_MODEL + col] = val;
            } else {
                y1[(size_t)row * D_MODEL + col] = val;
            }
        }
    }
}

// ---------------------------------------------------------------------------
// Kernel 7: LayerNorm over last dim (512); in2 optional (summed partials);
// outb optional bf16 shadow.
// ---------------------------------------------------------------------------
__global__ __launch_bounds__(256) void ln_kernel(
    const float* __restrict__ in, const float* __restrict__ in2,
    const float* __restrict__ gamma, const float* __restrict__ beta,
    float* __restrict__ out, bf16* __restrict__ outb)
{
    int row = blockIdx.x;
    int tid = threadIdx.x;
    int lane = tid & 63, wid = tid >> 6;
    __shared__ float red[4];

    float v0 = in[(size_t)row * D_MODEL + tid];
    float v1 = in[(size_t)row * D_MODEL + tid + 256];
    if (in2) {
        v0 += in2[(size_t)row * D_MODEL + tid];
        v1 += in2[(size_t)row * D_MODEL + tid + 256];
    }

    float s = v0 + v1;
    #pragma unroll
    for (int off = 32; off; off >>= 1) s += __shfl_xor(s, off, 64);
    if (lane == 0) red[wid] = s;
    __syncthreads();
    if (tid == 0) red[0] = red[0] + red[1] + red[2] + red[3];
    __syncthreads();
    float mu = red[0] * (1.0f / D_MODEL);
    __syncthreads();

    float d0 = v0 - mu, d1 = v1 - mu;
    float s2 = d0 * d0 + d1 * d1;
    #pragma unroll
    for (int off = 32; off; off >>= 1) s2 += __shfl_xor(s2, off, 64);
    if (lane == 0) red[wid] = s2;
    __syncthreads();
    if (tid == 0) red[0] = red[0] + red[1] + red[2] + red[3];
    __syncthreads();
    float var = red[0] * (1.0f / D_MODEL);
    float inv = rsqrtf(var + LN_EPS);

    float o0 = d0 * inv * gamma[tid] + beta[tid];
    float o1 = d1 * inv * gamma[tid + 256] + beta[tid + 256];
    out[(size_t)row * D_MODEL + tid]       = o0;
    out[(size_t)row * D_MODEL + tid + 256] = o1;
    if (outb) {
        outb[(size_t)row * D_MODEL + tid]       = __float2bfloat16(o0);
        outb[(size_t)row * D_MODEL + tid + 256] = __float2bfloat16(o1);
    }
}

// ---------------------------------------------------------------------------
extern "C" void kernel_launch(void* const* d_in, const int* in_sizes, int n_in,
                              void* d_out, int out_size, void* d_ws, size_t ws_size,
                              hipStream_t stream)
{
    const int*   tokens = (const int*)  d_in[0];
    const float* emb    = (const float*)d_in[1];
    const float* Wq     = (const float*)d_in[2];
    const float* bq     = (const float*)d_in[3];
    const float* Wk     = (const float*)d_in[4];
    const float* bk     = (const float*)d_in[5];
    const float* Wv     = (const float*)d_in[6];
    const float* bv     = (const float*)d_in[7];
    const float* ascale = (const float*)d_in[8];
    const float* Wo     = (const float*)d_in[9];
    const float* bo     = (const float*)d_in[10];
    const float* g1     = (const float*)d_in[11];
    const float* beta1  = (const float*)d_in[12];
    const float* W1     = (const float*)d_in[13];
    const float* bf1    = (const float*)d_in[14];
    const float* W2     = (const float*)d_in[15];
    const float* bf2    = (const float*)d_in[16];
    const float* g2     = (const float*)d_in[17];
    const float* beta2  = (const float*)d_in[18];

    float* out = (float*)d_out;
    float* ws  = (float*)d_ws;

    const size_t SZ = (size_t)NROWS * D_MODEL;   // 393216

    float* x0     = ws;            // embed out; Wo resid; then y1 (ffdown z=1)
    float* aexp   = ws + 1 * SZ;   // exp(2q); dead after scorepv -> t1 (wo out)
    float* bexp   = ws + 2 * SZ;   // exp(2k); dead after scorepv -> x1 (LN1 out)
    float* attn_q = ws + 3 * SZ;   // [4][NROWS][D_MODEL] f32 quarter partials
    float* t1 = aexp;
    float* x1 = bexp;
    float* y0 = x1;                // in-place: thread reads resid then writes
    float* y1 = x0;

    bf16* x0b   = (bf16*)(ws + 7 * SZ);
    bf16* x1b   = x0b + SZ;
    bf16* hb    = x1b + SZ;                          // NROWS * D_FF
    bf16* vbb   = hb + (size_t)NROWS * D_FF;         // [NROWS][D_MODEL]
    bf16* wqt   = vbb + SZ;
    bf16* wkt   = wqt + (size_t)D_MODEL * D_MODEL;
    bf16* wvt   = wkt + (size_t)D_MODEL * D_MODEL;
    bf16* wot   = wvt + (size_t)D_MODEL * D_MODEL;
    bf16* w1t   = wot + (size_t)D_MODEL * D_MODEL;   // [D_FF][D_MODEL]
    bf16* w2t   = w1t + (size_t)D_MODEL * D_FF;      // [D_MODEL][D_FF]
    float* Sp   = (float*)(w2t + (size_t)D_FF * D_MODEL);  // [NROWS][4]

    // 1. weight transposes + embed/PE
    prep_kernel<<<3072 + NROWS, 256, 0, stream>>>(
        tokens, emb, Wq, Wk, Wv, Wo, W1, W2,
        wqt, wkt, wvt, wot, w1t, w2t, x0, x0b);

    // 2. fused QKV (z: 0->aexp, 1->bexp, 2->vb bf16 plain)
    qkv_mfma_kernel<<<dim3(D_MODEL / 64, NROWS / 32, 3), 256, 0, stream>>>(
        x0b, wqt, wkt, wvt, bq, bk, bv, aexp, bexp, vbb);

    // 3. fused score + PV quarter-partials + Sp
    scorepv_kernel<<<dim3(NROWS / 4, 4), 512, 0, stream>>>(
        aexp, bexp, ascale, vbb, attn_q, Sp);

    // 4. Wo (quarter-combine + normalize + GEMM + bias + resid) -> t1
    wo_kernel<<<dim3(D_MODEL / 64, NROWS / 32), 256, 0, stream>>>(
        attn_q, Sp, wot, bo, x0, t1);

    // 5. LayerNorm 1 -> x1 f32 + x1b bf16
    ln_kernel<<<NROWS, 256, 0, stream>>>(t1, nullptr, g1, beta1, x1, x1b);

    // 6. FF up + ReLU -> hb bf16
    mfma_gemm_kernel<<<dim3(D_FF / 64, NROWS / 32), 256, 0, stream>>>(
        x1b, w1t, bf1, hb, D_MODEL, D_FF, 1);

    // 7. FF down, 2-way K-split: y0 = partial+bias+resid (in-place x1), y1 = partial
    ffdown_kernel<<<dim3(D_MODEL / 64, NROWS / 32, 2), 256, 0, stream>>>(
        hb, w2t, bf2, x1, y0, y1);

    // 8. LayerNorm 2 over (y0 + y1) -> out
    ln_kernel<<<NROWS, 256, 0, stream>>>(y0, y1, g2, beta2, out, nullptr);
}

// Round 11
// 123.839 us; speedup vs baseline: 1.0835x; 1.0538x over previous
//
#include <hip/hip_runtime.h>
#include <hip/hip_bf16.h>
#include <math.h>

#define D_MODEL 512
#define D_FF    2048
#define NBATCH  2
#define NSEQ    384
#define NROWS   (NBATCH * NSEQ)
#define LN_EPS  1e-6f

typedef __attribute__((ext_vector_type(8))) short short8;
typedef __attribute__((ext_vector_type(4))) short short4v;
typedef __attribute__((ext_vector_type(4))) float f32x4;
typedef __hip_bfloat16 bf16;

static __device__ __forceinline__ short bfb(float x) {
    bf16 h = __float2bfloat16(x);
    return *reinterpret_cast<short*>(&h);
}

#define MFMA16(a, b, c) __builtin_amdgcn_mfma_f32_16x16x32_bf16((a), (b), (c), 0, 0, 0)

// ---------------------------------------------------------------------------
// Kernel 1: fused prep. Blocks 0..3071: weight transpose W[K][N]f32->Wt[N][K]bf16.
// Blocks 3072..3839: embed+PE row (native trig).
// ---------------------------------------------------------------------------
__global__ __launch_bounds__(256) void prep_kernel(
    const int* __restrict__ tokens, const float* __restrict__ emb,
    const float* __restrict__ Wq, const float* __restrict__ Wk,
    const float* __restrict__ Wv, const float* __restrict__ Wo,
    const float* __restrict__ W1, const float* __restrict__ W2,
    bf16* __restrict__ wqt, bf16* __restrict__ wkt, bf16* __restrict__ wvt,
    bf16* __restrict__ wot, bf16* __restrict__ w1t, bf16* __restrict__ w2t,
    float* __restrict__ x, bf16* __restrict__ xb)
{
    __shared__ float tile[32][33];
    int t = blockIdx.x;

    if (t < 3072) {
        const float* W; bf16* Wt; int K, N, bx, by;
        if (t < 1024) {
            int w = t >> 8, rem = t & 255;
            W  = (w == 0) ? Wq  : (w == 1) ? Wk  : (w == 2) ? Wv  : Wo;
            Wt = (w == 0) ? wqt : (w == 1) ? wkt : (w == 2) ? wvt : wot;
            K = 512; N = 512; bx = rem & 15; by = rem >> 4;
        } else if (t < 2048) {
            int rem = t - 1024;
            W = W1; Wt = w1t; K = 512; N = 2048; bx = rem & 63; by = rem >> 6;
        } else {
            int rem = t - 2048;
            W = W2; Wt = w2t; K = 2048; N = 512; bx = rem & 15; by = rem >> 4;
        }
        int tx = threadIdx.x & 31, ty = threadIdx.x >> 5;
        #pragma unroll
        for (int r = ty; r < 32; r += 8)
            tile[r][tx] = W[(size_t)(by * 32 + r) * N + bx * 32 + tx];
        __syncthreads();
        #pragma unroll
        for (int r = ty; r < 32; r += 8)
            Wt[(size_t)(bx * 32 + r) * K + by * 32 + tx] = __float2bfloat16(tile[tx][r]);
    } else {
        int row = t - 3072;              // b*NSEQ + n
        int n   = row % NSEQ;
        int tok = tokens[row];
        const float sqrtD = 22.627416997969522f; // sqrt(512)
        const float ESC   = 0.02595256324130752f; // log2(10000)/512
        for (int d = threadIdx.x; d < D_MODEL; d += 256) {
            float e   = emb[tok * D_MODEL + d] * sqrtD;
            float ang = (float)n * __builtin_amdgcn_exp2f(-(float)(d & ~1) * ESC);
            float pe  = (d & 1) ? __cosf(ang) : __sinf(ang);
            float val = e + pe;
            x [(size_t)row * D_MODEL + d] = val;
            xb[(size_t)row * D_MODEL + d] = __float2bfloat16(val);
        }
    }
}

// ---------------------------------------------------------------------------
// Kernel 2: fused QKV MFMA GEMM (no LDS). blockIdx.z selects q/k/v.
//  z=0: aexp = exp(2*(x@Wq+bq)); z=1: bexp = exp(2*(x@Wk+bk));
//  z=2: vT[b][d][j] = bf16(x@Wv+bv)   (transposed for PV MFMA B-operand)
// ---------------------------------------------------------------------------
__global__ __launch_bounds__(256) void qkv_mfma_kernel(
    const bf16* __restrict__ A,
    const bf16* __restrict__ wqt, const bf16* __restrict__ wkt, const bf16* __restrict__ wvt,
    const float* __restrict__ bq, const float* __restrict__ bk, const float* __restrict__ bv,
    float* __restrict__ aexp, float* __restrict__ bexp, bf16* __restrict__ vT)
{
    int z = blockIdx.z;
    const bf16*  Wt   = (z == 0) ? wqt : (z == 1) ? wkt : wvt;
    const float* bias = (z == 0) ? bq  : (z == 1) ? bk  : bv;

    int lane = threadIdx.x & 63, wid = threadIdx.x >> 6;
    int rowBase = blockIdx.y * 32 + (wid >> 1) * 16;
    int colBase = blockIdx.x * 64 + (wid & 1) * 32;

    const bf16* Ap  = A  + (size_t)(rowBase + (lane & 15)) * D_MODEL + ((lane >> 4) << 3);
    const bf16* Bp0 = Wt + (size_t)(colBase + (lane & 15)) * D_MODEL + ((lane >> 4) << 3);
    const bf16* Bp1 = Bp0 + (size_t)16 * D_MODEL;

    f32x4 acc0 = {0.f, 0.f, 0.f, 0.f};
    f32x4 acc1 = {0.f, 0.f, 0.f, 0.f};

    #pragma unroll 4
    for (int k0 = 0; k0 < D_MODEL; k0 += 32) {
        short8 a  = *reinterpret_cast<const short8*>(Ap  + k0);
        short8 b0 = *reinterpret_cast<const short8*>(Bp0 + k0);
        short8 b1 = *reinterpret_cast<const short8*>(Bp1 + k0);
        acc0 = MFMA16(a, b0, acc0);
        acc1 = MFMA16(a, b1, acc1);
    }

    int crow = rowBase + ((lane >> 4) << 2);
    int ccol = colBase + (lane & 15);

    if (z < 2) {
        float* C = (z == 0) ? aexp : bexp;
        #pragma unroll
        for (int r = 0; r < 4; ++r) {
            int row = crow + r;
            #pragma unroll
            for (int j = 0; j < 2; ++j) {
                int col = ccol + j * 16;
                float val = (j == 0 ? acc0[r] : acc1[r]) + bias[col];
                C[(size_t)row * D_MODEL + col] = __expf(2.0f * val);
            }
        }
    } else {
        int bb = crow / NSEQ;
        int jr = crow - bb * NSEQ;
        #pragma unroll
        for (int j = 0; j < 2; ++j) {
            int col = ccol + j * 16;
            short4v pk;
            #pragma unroll
            for (int r = 0; r < 4; ++r)
                pk[r] = bfb((j == 0 ? acc0[r] : acc1[r]) + bias[col]);
            size_t idx = ((size_t)bb * D_MODEL + col) * NSEQ + jr;
            *reinterpret_cast<short4v*>((short*)vT + idx) = pk;
        }
    }
}

// ---------------------------------------------------------------------------
// Kernel 3: score v2 — deferred batched reduction.
// u_ij = sum_d sv_d * rcp(a_id*b_jd+1) (pairwise-rcp halves rcp count).
// Partials for 3 t6-iters (24 u-values) accumulate in registers with
// compile-time indices; then 24 independent 6-stage butterflies (ILP-hidden),
// exp + E write + es accumulate. Twice per kernel.
// E = exp(u) bf16 unnormalized; Sp[row][quarter] = partial sums.
// grid (NROWS/4, 4); 512 thr. Lane owns d-slice [8l,8l+8); b-loads coalesced.
// ---------------------------------------------------------------------------
__global__ __launch_bounds__(512) void score_kernel(
    const float* __restrict__ aexp, const float* __restrict__ bexp,
    const float* __restrict__ scale, bf16* __restrict__ E,
    float* __restrict__ Sp)
{
    int ig   = blockIdx.x;
    int qt   = blockIdx.y;
    int row0 = ig * 4;
    int b    = row0 / NSEQ;
    int tid  = threadIdx.x;
    int lane = tid & 63, wid = tid >> 6;

    __shared__ float sred[8][4];

    const float* ap = aexp + (size_t)row0 * D_MODEL + lane * 8;
    float a[4][8];
    #pragma unroll
    for (int r = 0; r < 4; ++r) {
        float4 A0 = *(const float4*)(ap + (size_t)r * D_MODEL);
        float4 A1 = *(const float4*)(ap + (size_t)r * D_MODEL + 4);
        a[r][0]=A0.x; a[r][1]=A0.y; a[r][2]=A0.z; a[r][3]=A0.w;
        a[r][4]=A1.x; a[r][5]=A1.y; a[r][6]=A1.z; a[r][7]=A1.w;
    }
    float4 S0 = *(const float4*)(scale + lane * 8);
    float4 S1 = *(const float4*)(scale + lane * 8 + 4);
    float sv[8] = {-2.0f*S0.x,-2.0f*S0.y,-2.0f*S0.z,-2.0f*S0.w,
                   -2.0f*S1.x,-2.0f*S1.y,-2.0f*S1.z,-2.0f*S1.w};

    const float* kb = bexp + (size_t)b * NSEQ * D_MODEL + lane * 8;
    int jb = qt * 96 + wid;

    float es[4] = {0.f, 0.f, 0.f, 0.f};

    #pragma unroll
    for (int half = 0; half < 2; ++half) {
        float uacc[3][4][2];
        #pragma unroll
        for (int t3 = 0; t3 < 3; ++t3)
            #pragma unroll
            for (int r = 0; r < 4; ++r) {
                uacc[t3][r][0] = 0.f; uacc[t3][r][1] = 0.f;
            }

        // ---- compute partials for 3 iterations (no reduction yet)
        #pragma unroll
        for (int t3 = 0; t3 < 3; ++t3) {
            int t6 = half * 3 + t3;
            int j0 = jb + t6 * 16;
            int j1 = j0 + 8;
            const float4* kp0 = (const float4*)(kb + (size_t)j0 * D_MODEL);
            const float4* kp1 = (const float4*)(kb + (size_t)j1 * D_MODEL);
            float4 xa = kp0[0], xc = kp0[1];
            float4 ya = kp1[0], yc = kp1[1];
            float b0[8] = {xa.x,xa.y,xa.z,xa.w,xc.x,xc.y,xc.z,xc.w};
            float b1[8] = {ya.x,ya.y,ya.z,ya.w,yc.x,yc.y,yc.z,yc.w};

            #pragma unroll
            for (int up = 0; up < 4; ++up) {
                int d0 = up * 2, d1 = d0 + 1;
                #pragma unroll
                for (int js = 0; js < 2; ++js) {
                    float xx = js ? b1[d0] : b0[d0];
                    float yy = js ? b1[d1] : b0[d1];
                    #pragma unroll
                    for (int r = 0; r < 4; ++r) {
                        float p   = fmaf(a[r][d0], xx, 1.0f);
                        float q   = fmaf(a[r][d1], yy, 1.0f);
                        float num = fmaf(sv[d0], q, sv[d1] * p);
                        uacc[t3][r][js] = fmaf(num, __builtin_amdgcn_rcpf(p * q),
                                               uacc[t3][r][js]);
                    }
                }
            }
        }

        // ---- 24 independent butterflies (6 stages, ILP-hidden)
        #pragma unroll
        for (int off = 1; off < 64; off <<= 1)
            #pragma unroll
            for (int t3 = 0; t3 < 3; ++t3)
                #pragma unroll
                for (int r = 0; r < 4; ++r) {
                    uacc[t3][r][0] += __shfl_xor(uacc[t3][r][0], off, 64);
                    uacc[t3][r][1] += __shfl_xor(uacc[t3][r][1], off, 64);
                }

        // ---- exp + write + es
        #pragma unroll
        for (int t3 = 0; t3 < 3; ++t3) {
            int t6 = half * 3 + t3;
            int j0 = jb + t6 * 16;
            int j1 = j0 + 8;
            #pragma unroll
            for (int r = 0; r < 4; ++r) {
                float e0 = __expf(uacc[t3][r][0]);
                float e1 = __expf(uacc[t3][r][1]);
                if (lane == 0) {
                    E[(size_t)(row0 + r) * NSEQ + j0] = __float2bfloat16(e0);
                    E[(size_t)(row0 + r) * NSEQ + j1] = __float2bfloat16(e1);
                }
                es[r] += e0 + e1;
            }
        }
    }

    if (lane == 0) {
        sred[wid][0] = es[0]; sred[wid][1] = es[1];
        sred[wid][2] = es[2]; sred[wid][3] = es[3];
    }
    __syncthreads();
    if (tid < 4) {
        float s = 0.0f;
        #pragma unroll
        for (int w = 0; w < 8; ++w) s += sred[w][tid];
        Sp[(size_t)(row0 + tid) * 4 + qt] = s;
    }
}

// ---------------------------------------------------------------------------
// Kernel 4: PV MFMA + normalize: attnb[b,i,d] = (sum_j E[b,i,j] v[b,j,d]) / S_i
// ---------------------------------------------------------------------------
__global__ __launch_bounds__(256) void pv_mfma_kernel(
    const bf16* __restrict__ E, const bf16* __restrict__ vT,
    const float* __restrict__ Sp, bf16* __restrict__ attnb)
{
    int z = blockIdx.z;
    int lane = threadIdx.x & 63, wid = threadIdx.x >> 6;
    int rowBase = blockIdx.y * 32 + (wid >> 1) * 16;
    int colBase = blockIdx.x * 64 + (wid & 1) * 32;

    const bf16* Ap  = E  + ((size_t)z * NSEQ + rowBase + (lane & 15)) * NSEQ + ((lane >> 4) << 3);
    const bf16* Bp0 = vT + ((size_t)z * D_MODEL + colBase + (lane & 15)) * NSEQ + ((lane >> 4) << 3);
    const bf16* Bp1 = Bp0 + (size_t)16 * NSEQ;

    f32x4 acc0 = {0.f, 0.f, 0.f, 0.f};
    f32x4 acc1 = {0.f, 0.f, 0.f, 0.f};

    #pragma unroll 4
    for (int k0 = 0; k0 < NSEQ; k0 += 32) {
        short8 a  = *reinterpret_cast<const short8*>(Ap  + k0);
        short8 b0 = *reinterpret_cast<const short8*>(Bp0 + k0);
        short8 b1 = *reinterpret_cast<const short8*>(Bp1 + k0);
        acc0 = MFMA16(a, b0, acc0);
        acc1 = MFMA16(a, b1, acc1);
    }

    int crow = rowBase + ((lane >> 4) << 2);
    int ccol = colBase + (lane & 15);
    #pragma unroll
    for (int r = 0; r < 4; ++r) {
        int grow = z * NSEQ + crow + r;
        float4 sp4 = *(const float4*)(Sp + (size_t)grow * 4);
        float Sinv = 1.0f / (sp4.x + sp4.y + sp4.z + sp4.w);
        #pragma unroll
        for (int j = 0; j < 2; ++j)
            attnb[(size_t)grow * D_MODEL + ccol + j * 16] =
                __float2bfloat16((j == 0 ? acc0[r] : acc1[r]) * Sinv);
    }
}

// ---------------------------------------------------------------------------
// Kernel 5: generic bf16 MFMA GEMM (no LDS): C = A @ Wt^T + bias (+resid)(+relu)
// ---------------------------------------------------------------------------
__global__ __launch_bounds__(256) void mfma_gemm_kernel(
    const bf16* __restrict__ A, const bf16* __restrict__ Wt,
    const float* __restrict__ bias, const float* __restrict__ resid,
    float* __restrict__ Cf, bf16* __restrict__ Cb,
    int K, int N, int relu)
{
    int lane = threadIdx.x & 63, wid = threadIdx.x >> 6;
    int rowBase = blockIdx.y * 32 + (wid >> 1) * 16;
    int colBase = blockIdx.x * 64 + (wid & 1) * 32;

    const bf16* Ap  = A  + (size_t)(rowBase + (lane & 15)) * K + ((lane >> 4) << 3);
    const bf16* Bp0 = Wt + (size_t)(colBase + (lane & 15)) * K + ((lane >> 4) << 3);
    const bf16* Bp1 = Bp0 + (size_t)16 * K;

    f32x4 acc0 = {0.f, 0.f, 0.f, 0.f};
    f32x4 acc1 = {0.f, 0.f, 0.f, 0.f};

    #pragma unroll 4
    for (int k0 = 0; k0 < K; k0 += 32) {
        short8 a  = *reinterpret_cast<const short8*>(Ap  + k0);
        short8 b0 = *reinterpret_cast<const short8*>(Bp0 + k0);
        short8 b1 = *reinterpret_cast<const short8*>(Bp1 + k0);
        acc0 = MFMA16(a, b0, acc0);
        acc1 = MFMA16(a, b1, acc1);
    }

    int crow = rowBase + ((lane >> 4) << 2);
    int ccol = colBase + (lane & 15);
    #pragma unroll
    for (int r = 0; r < 4; ++r) {
        int row = crow + r;
        #pragma unroll
        for (int j = 0; j < 2; ++j) {
            int col = ccol + j * 16;
            float val = (j == 0 ? acc0[r] : acc1[r]) + bias[col];
            if (resid) val += resid[(size_t)row * N + col];
            if (relu)  val = fmaxf(val, 0.0f);
            if (Cf) Cf[(size_t)row * N + col] = val;
            if (Cb) Cb[(size_t)row * N + col] = __float2bfloat16(val);
        }
    }
}

// ---------------------------------------------------------------------------
// Kernel 6: FF-down with 2-way K-split (z = K-half). z=0 adds bias+resid -> y0;
// z=1 plain partial -> y1. Combined in LN2.
// ---------------------------------------------------------------------------
__global__ __launch_bounds__(256) void ffdown_kernel(
    const bf16* __restrict__ A, const bf16* __restrict__ Wt,
    const float* __restrict__ bias, const float* __restrict__ resid,
    float* __restrict__ y0, float* __restrict__ y1)
{
    int z = blockIdx.z;
    int kbeg = z * (D_FF / 2);
    int lane = threadIdx.x & 63, wid = threadIdx.x >> 6;
    int rowBase = blockIdx.y * 32 + (wid >> 1) * 16;
    int colBase = blockIdx.x * 64 + (wid & 1) * 32;

    const bf16* Ap  = A  + (size_t)(rowBase + (lane & 15)) * D_FF + kbeg + ((lane >> 4) << 3);
    const bf16* Bp0 = Wt + (size_t)(colBase + (lane & 15)) * D_FF + kbeg + ((lane >> 4) << 3);
    const bf16* Bp1 = Bp0 + (size_t)16 * D_FF;

    f32x4 acc0 = {0.f, 0.f, 0.f, 0.f};
    f32x4 acc1 = {0.f, 0.f, 0.f, 0.f};

    #pragma unroll 4
    for (int k0 = 0; k0 < D_FF / 2; k0 += 32) {
        short8 a  = *reinterpret_cast<const short8*>(Ap  + k0);
        short8 b0 = *reinterpret_cast<const short8*>(Bp0 + k0);
        short8 b1 = *reinterpret_cast<const short8*>(Bp1 + k0);
        acc0 = MFMA16(a, b0, acc0);
        acc1 = MFMA16(a, b1, acc1);
    }

    int crow = rowBase + ((lane >> 4) << 2);
    int ccol = colBase + (lane & 15);
    #pragma unroll
    for (int r = 0; r < 4; ++r) {
        int row = crow + r;
        #pragma unroll
        for (int j = 0; j < 2; ++j) {
            int col = ccol + j * 16;
            float val = (j == 0 ? acc0[r] : acc1[r]);
            if (z == 0) {
                val += bias[col] + resid[(size_t)row * D_MODEL + col];
                y0[(size_t)row * D_MODEL + col] = val;
            } else {
                y1[(size_t)row * D_MODEL + col] = val;
            }
        }
    }
}

// ---------------------------------------------------------------------------
// Kernel 7: LayerNorm over last dim (512); in2 optional; outb optional bf16.
// ---------------------------------------------------------------------------
__global__ __launch_bounds__(256) void ln_kernel(
    const float* __restrict__ in, const float* __restrict__ in2,
    const float* __restrict__ gamma, const float* __restrict__ beta,
    float* __restrict__ out, bf16* __restrict__ outb)
{
    int row = blockIdx.x;
    int tid = threadIdx.x;
    int lane = tid & 63, wid = tid >> 6;
    __shared__ float red[4];

    float v0 = in[(size_t)row * D_MODEL + tid];
    float v1 = in[(size_t)row * D_MODEL + tid + 256];
    if (in2) {
        v0 += in2[(size_t)row * D_MODEL + tid];
        v1 += in2[(size_t)row * D_MODEL + tid + 256];
    }

    float s = v0 + v1;
    #pragma unroll
    for (int off = 32; off; off >>= 1) s += __shfl_xor(s, off, 64);
    if (lane == 0) red[wid] = s;
    __syncthreads();
    if (tid == 0) red[0] = red[0] + red[1] + red[2] + red[3];
    __syncthreads();
    float mu = red[0] * (1.0f / D_MODEL);
    __syncthreads();

    float d0 = v0 - mu, d1 = v1 - mu;
    float s2 = d0 * d0 + d1 * d1;
    #pragma unroll
    for (int off = 32; off; off >>= 1) s2 += __shfl_xor(s2, off, 64);
    if (lane == 0) red[wid] = s2;
    __syncthreads();
    if (tid == 0) red[0] = red[0] + red[1] + red[2] + red[3];
    __syncthreads();
    float var = red[0] * (1.0f / D_MODEL);
    float inv = rsqrtf(var + LN_EPS);

    float o0 = d0 * inv * gamma[tid] + beta[tid];
    float o1 = d1 * inv * gamma[tid + 256] + beta[tid + 256];
    out[(size_t)row * D_MODEL + tid]       = o0;
    out[(size_t)row * D_MODEL + tid + 256] = o1;
    if (outb) {
        outb[(size_t)row * D_MODEL + tid]       = __float2bfloat16(o0);
        outb[(size_t)row * D_MODEL + tid + 256] = __float2bfloat16(o1);
    }
}

// ---------------------------------------------------------------------------
extern "C" void kernel_launch(void* const* d_in, const int* in_sizes, int n_in,
                              void* d_out, int out_size, void* d_ws, size_t ws_size,
                              hipStream_t stream)
{
    const int*   tokens = (const int*)  d_in[0];
    const float* emb    = (const float*)d_in[1];
    const float* Wq     = (const float*)d_in[2];
    const float* bq     = (const float*)d_in[3];
    const float* Wk     = (const float*)d_in[4];
    const float* bk     = (const float*)d_in[5];
    const float* Wv     = (const float*)d_in[6];
    const float* bv     = (const float*)d_in[7];
    const float* ascale = (const float*)d_in[8];
    const float* Wo     = (const float*)d_in[9];
    const float* bo     = (const float*)d_in[10];
    const float* g1     = (const float*)d_in[11];
    const float* beta1  = (const float*)d_in[12];
    const float* W1     = (const float*)d_in[13];
    const float* bf1    = (const float*)d_in[14];
    const float* W2     = (const float*)d_in[15];
    const float* bf2    = (const float*)d_in[16];
    const float* g2     = (const float*)d_in[17];
    const float* beta2  = (const float*)d_in[18];

    float* out = (float*)d_out;
    float* ws  = (float*)d_ws;

    const size_t SZ = (size_t)NROWS * D_MODEL;   // 393216

    float* x0   = ws;            // embed out; Wo resid; then y1 (ffdown z=1)
    float* aexp = ws + 1 * SZ;   // exp(2q); dead after score -> t1 (wo out)
    float* bexp = ws + 2 * SZ;   // exp(2k); dead after score -> x1 (LN1 out)
    float* t1 = aexp;
    float* x1 = bexp;
    float* y0 = x1;              // in-place: thread reads resid then writes
    float* y1 = x0;              // x0 dead after wo

    bf16* x0b   = (bf16*)(ws + 3 * SZ);
    bf16* attnb = x0b + SZ;
    bf16* x1b   = attnb + SZ;
    bf16* hb    = x1b + SZ;                          // NROWS * D_FF
    bf16* Eb    = hb + (size_t)NROWS * D_FF;         // 2*384*384
    bf16* vTb   = Eb + (size_t)NBATCH * NSEQ * NSEQ; // 2*512*384
    bf16* wqt   = vTb + (size_t)NBATCH * D_MODEL * NSEQ;
    bf16* wkt   = wqt + (size_t)D_MODEL * D_MODEL;
    bf16* wvt   = wkt + (size_t)D_MODEL * D_MODEL;
    bf16* wot   = wvt + (size_t)D_MODEL * D_MODEL;
    bf16* w1t   = wot + (size_t)D_MODEL * D_MODEL;   // [D_FF][D_MODEL]
    bf16* w2t   = w1t + (size_t)D_MODEL * D_FF;      // [D_MODEL][D_FF]
    float* Sp   = (float*)(w2t + (size_t)D_FF * D_MODEL);  // [NROWS][4]

    // 1. weight transposes + embed/PE
    prep_kernel<<<3072 + NROWS, 256, 0, stream>>>(
        tokens, emb, Wq, Wk, Wv, Wo, W1, W2,
        wqt, wkt, wvt, wot, w1t, w2t, x0, x0b);

    // 2. fused QKV (z: 0->aexp, 1->bexp, 2->vT bf16)
    qkv_mfma_kernel<<<dim3(D_MODEL / 64, NROWS / 32, 3), 256, 0, stream>>>(
        x0b, wqt, wkt, wvt, bq, bk, bv, aexp, bexp, vTb);

    // 3. score v2 (deferred batched reduction) -> E + Sp
    score_kernel<<<dim3(NROWS / 4, 4), 512, 0, stream>>>(aexp, bexp, ascale, Eb, Sp);

    // 4. PV + normalize -> attnb bf16
    pv_mfma_kernel<<<dim3(D_MODEL / 64, NSEQ / 32, NBATCH), 256, 0, stream>>>(
        Eb, vTb, Sp, attnb);

    // 5. output projection + residual -> t1 f32
    mfma_gemm_kernel<<<dim3(D_MODEL / 64, NROWS / 32), 256, 0, stream>>>(
        attnb, wot, bo, x0, t1, nullptr, D_MODEL, D_MODEL, 0);

    // 6. LayerNorm 1 -> x1 f32 + x1b bf16
    ln_kernel<<<NROWS, 256, 0, stream>>>(t1, nullptr, g1, beta1, x1, x1b);

    // 7. FF up + ReLU -> hb bf16
    mfma_gemm_kernel<<<dim3(D_FF / 64, NROWS / 32), 256, 0, stream>>>(
        x1b, w1t, bf1, nullptr, nullptr, hb, D_MODEL, D_FF, 1);

    // 8. FF down, 2-way K-split: y0 = partial+bias+resid (in-place x1), y1 = partial
    ffdown_kernel<<<dim3(D_MODEL / 64, NROWS / 32, 2), 256, 0, stream>>>(
        hb, w2t, bf2, x1, y0, y1);

    // 9. LayerNorm 2 over (y0 + y1) -> out
    ln_kernel<<<NROWS, 256, 0, stream>>>(y0, y1, g2, beta2, out, nullptr);
}